// Round 1
// baseline (234.838 us; speedup 1.0000x reference)
//
#include <hip/hip_runtime.h>

// Problem constants
#define NB      20000      // nodes per batch
#define BATCH   4
#define KNN     16
#define DD      128        // embedding dim
#define K3      384        // 3*D
#define M_TOTAL (BATCH*NB) // 80000 rows
#define BM      64         // nodes per block
#define FP      392        // feats LDS row stride (bf16 elems), padded from 384
#define HP      136        // h LDS row stride (bf16 elems), padded from 128

typedef __attribute__((ext_vector_type(8))) short    bf16x8;
typedef __attribute__((ext_vector_type(4))) float    f32x4;
typedef __attribute__((ext_vector_type(4))) unsigned short u16x4;

__device__ __forceinline__ unsigned short f2bf(float f) {
    unsigned int u = __float_as_uint(f);
    u += 0x7fffu + ((u >> 16) & 1u);           // round-to-nearest-even
    return (unsigned short)(u >> 16);
}

// ---- prep: W1 [384][128] f32 -> W1T bf16 [128 col][384 k]
//            W2 [128][128] f32 -> W2T bf16 [128 col][128 k]
__global__ __launch_bounds__(256) void nr_prep_weights(
    const float* __restrict__ W1, const float* __restrict__ W2,
    unsigned short* __restrict__ W1T, unsigned short* __restrict__ W2T)
{
    int tid = blockIdx.x * 256 + threadIdx.x;
    if (tid < 128 * K3) {
        int col = tid / K3, k = tid % K3;
        W1T[tid] = f2bf(W1[k * DD + col]);
    } else {
        int t2 = tid - 128 * K3;               // < 128*128
        int col = t2 / DD, k = t2 % DD;
        W2T[t2] = f2bf(W2[k * DD + col]);
    }
}

__global__ __launch_bounds__(256, 2) void nr_fused_main(
    const float* __restrict__ emb, const int* __restrict__ knn,
    const unsigned short* __restrict__ W1T, const unsigned short* __restrict__ W2T,
    const float* __restrict__ b1, const float* __restrict__ b2,
    float* __restrict__ out)
{
    __shared__ unsigned short feats[BM * FP];   // 50176 B
    __shared__ unsigned short hlds [BM * HP];   // 17408 B

    const int t      = threadIdx.x;
    const int m_base = blockIdx.x * BM;

    // -------- Phase 1: gather 16 neighbors, mean, build feats (bf16 in LDS)
    {
        const int node_local = t >> 2;          // 0..63
        const int dpart      = t & 3;           // 0..3 -> 32 dims each
        const int m          = m_base + node_local;
        const int b          = m / NB;
        const float4* xp = (const float4*)(emb + (long long)m * DD + dpart * 32);
        float4 xv[8], sm[8];
        #pragma unroll
        for (int j = 0; j < 8; ++j) {
            xv[j] = xp[j];
            sm[j] = make_float4(0.f, 0.f, 0.f, 0.f);
        }
        int idx[KNN];
        const int4* kp4 = (const int4*)(knn + (long long)m * KNN);
        #pragma unroll
        for (int q = 0; q < 4; ++q) {
            int4 v = kp4[q];
            idx[4*q+0] = v.x; idx[4*q+1] = v.y; idx[4*q+2] = v.z; idx[4*q+3] = v.w;
        }
        const long long bbase = (long long)b * NB * DD;
        #pragma unroll
        for (int k = 0; k < KNN; ++k) {
            const float4* np = (const float4*)(emb + bbase + (long long)idx[k] * DD + dpart * 32);
            #pragma unroll
            for (int j = 0; j < 8; ++j) {
                float4 v = np[j];
                sm[j].x += v.x; sm[j].y += v.y; sm[j].z += v.z; sm[j].w += v.w;
            }
        }
        unsigned short* frow = feats + node_local * FP + dpart * 32;
        #pragma unroll
        for (int j = 0; j < 8; ++j) {
            float mx = sm[j].x * 0.0625f, my = sm[j].y * 0.0625f;
            float mz = sm[j].z * 0.0625f, mw = sm[j].w * 0.0625f;
            u16x4 px, pm, pd;
            px[0]=f2bf(xv[j].x); px[1]=f2bf(xv[j].y); px[2]=f2bf(xv[j].z); px[3]=f2bf(xv[j].w);
            pm[0]=f2bf(mx);      pm[1]=f2bf(my);      pm[2]=f2bf(mz);      pm[3]=f2bf(mw);
            pd[0]=f2bf(xv[j].x-mx); pd[1]=f2bf(xv[j].y-my); pd[2]=f2bf(xv[j].z-mz); pd[3]=f2bf(xv[j].w-mw);
            *(u16x4*)(frow + j*4)        = px;   // x
            *(u16x4*)(frow + 128 + j*4)  = pm;   // mean
            *(u16x4*)(frow + 256 + j*4)  = pd;   // x - mean
        }
    }
    __syncthreads();

    // -------- Phase 2: GEMM1  h_pre = feats @ W1   (per-wave 16 rows x 128 cols)
    const int wave = t >> 6;                    // 0..3
    const int lane = t & 63;
    const int lrow = lane & 15;                 // A row / B col / D col
    const int lk   = lane >> 4;                 // 0..3

    f32x4 acc[8];
    #pragma unroll
    for (int f = 0; f < 8; ++f) acc[f] = (f32x4){0.f, 0.f, 0.f, 0.f};

    {
        const unsigned short* abase = feats + (wave * 16 + lrow) * FP + lk * 8;
        #pragma unroll
        for (int ks = 0; ks < 12; ++ks) {
            bf16x8 af = *(const bf16x8*)(abase + ks * 32);
            #pragma unroll
            for (int f = 0; f < 8; ++f) {
                int col = f * 16 + lrow;
                bf16x8 bf = *(const bf16x8*)(W1T + (long long)col * K3 + ks * 32 + lk * 8);
                acc[f] = __builtin_amdgcn_mfma_f32_16x16x32_bf16(af, bf, acc[f], 0, 0, 0);
            }
        }
    }

    // epilogue 1: bias + exact GELU -> hlds (bf16)
    #pragma unroll
    for (int f = 0; f < 8; ++f) {
        int col = f * 16 + lrow;
        float bb = b1[col];
        #pragma unroll
        for (int r = 0; r < 4; ++r) {
            int row = wave * 16 + lk * 4 + r;
            float xg = acc[f][r] + bb;
            float hv = 0.5f * xg * (1.0f + erff(xg * 0.70710678118654752f));
            hlds[row * HP + col] = f2bf(hv);
        }
    }
    __syncthreads();

    // -------- Phase 3: GEMM2  upd = h @ W2
    f32x4 acc2[8];
    #pragma unroll
    for (int f = 0; f < 8; ++f) acc2[f] = (f32x4){0.f, 0.f, 0.f, 0.f};

    {
        const unsigned short* abase = hlds + (wave * 16 + lrow) * HP + lk * 8;
        #pragma unroll
        for (int ks = 0; ks < 4; ++ks) {
            bf16x8 af = *(const bf16x8*)(abase + ks * 32);
            #pragma unroll
            for (int f = 0; f < 8; ++f) {
                int col = f * 16 + lrow;
                bf16x8 bf = *(const bf16x8*)(W2T + col * DD + ks * 32 + lk * 8);
                acc2[f] = __builtin_amdgcn_mfma_f32_16x16x32_bf16(af, bf, acc2[f], 0, 0, 0);
            }
        }
    }

    // epilogue 2: residual + bias, fp32 out
    #pragma unroll
    for (int f = 0; f < 8; ++f) {
        int col = f * 16 + lrow;
        float bb = b2[col];
        #pragma unroll
        for (int r = 0; r < 4; ++r) {
            int row = wave * 16 + lk * 4 + r;
            long long o = (long long)(m_base + row) * DD + col;
            out[o] = emb[o] + acc2[f][r] + bb;
        }
    }
}

extern "C" void kernel_launch(void* const* d_in, const int* in_sizes, int n_in,
                              void* d_out, int out_size, void* d_ws, size_t ws_size,
                              hipStream_t stream) {
    const float* emb = (const float*)d_in[0];   // [B,N,D] f32
    const int*   knn = (const int*)  d_in[1];   // [B,N,K] i32
    const float* W1  = (const float*)d_in[2];   // [384,128]
    const float* b1  = (const float*)d_in[3];   // [128]
    const float* W2  = (const float*)d_in[4];   // [128,128]
    const float* b2  = (const float*)d_in[5];   // [128]
    float* out = (float*)d_out;

    unsigned short* W1T = (unsigned short*)d_ws;            // 128*384 bf16
    unsigned short* W2T = W1T + 128 * K3;                   // 128*128 bf16

    // prep: 65536 elements total
    nr_prep_weights<<<(128*K3 + 128*DD) / 256, 256, 0, stream>>>(W1, W2, W1T, W2T);

    nr_fused_main<<<M_TOTAL / BM, 256, 0, stream>>>(emb, knn, W1T, W2T, b1, b2, out);
}

// Round 4
// 130.859 us; speedup vs baseline: 1.7946x; 1.7946x over previous
//
#include <hip/hip_runtime.h>

// Problem constants
#define NB      20000      // nodes per batch
#define BATCH   4
#define KNN     16
#define DD      128        // embedding dim
#define K3      384        // 3*D
#define M_TOTAL (BATCH*NB) // 80000 rows
#define BM      64         // nodes per block
#define FP      392        // feats LDS row stride (bf16 elems), padded from 384
#define HP      136        // h LDS row stride (bf16 elems), padded from 128

typedef __attribute__((ext_vector_type(8))) short          bf16x8;
typedef __attribute__((ext_vector_type(4))) float          f32x4;
typedef __attribute__((ext_vector_type(4))) int            i32x4;
typedef __attribute__((ext_vector_type(8))) unsigned short u16x8;

__device__ __forceinline__ unsigned short f2bf(float f) {
    unsigned int u = __float_as_uint(f);
    u += 0x7fffu + ((u >> 16) & 1u);           // round-to-nearest-even
    return (unsigned short)(u >> 16);
}
__device__ __forceinline__ float bf2f(unsigned short u) {
    return __uint_as_float((unsigned int)u << 16);
}

// ---- weights prep: W1 [384][128] -> W1T bf16 [col][k]; W2 -> W2T (256 blocks)
__global__ __launch_bounds__(256) void nr_prep_w(
    const float* __restrict__ W1, const float* __restrict__ W2,
    unsigned short* __restrict__ W1T, unsigned short* __restrict__ W2T)
{
    int tid = blockIdx.x * 256 + threadIdx.x;   // < 65536
    if (tid < 128 * K3) {
        int col = tid / K3, k = tid % K3;
        W1T[tid] = f2bf(W1[k * DD + col]);
    } else {
        int t2 = tid - 128 * K3;
        int col = t2 / DD, k = t2 % DD;
        W2T[t2] = f2bf(W2[k * DD + col]);
    }
}

// ---- emb prep: contiguous f32 -> bf16, 8 elems/thread
__global__ __launch_bounds__(256) void nr_prep_emb(
    const float* __restrict__ src, unsigned short* __restrict__ dst)
{
    long long i = ((long long)blockIdx.x * 256 + threadIdx.x) * 8;
    const float4* p = (const float4*)(src + i);
    float4 a = p[0], b = p[1];
    u16x8 o;
    o[0]=f2bf(a.x); o[1]=f2bf(a.y); o[2]=f2bf(a.z); o[3]=f2bf(a.w);
    o[4]=f2bf(b.x); o[5]=f2bf(b.y); o[6]=f2bf(b.z); o[7]=f2bf(b.w);
    *(u16x8*)(dst + i) = o;
}

// MODE 0: full bf16 table (embh holds all B*N rows, indexed globally)
// MODE 1: per-batch bf16 table (embh holds NB rows of batch m_start/NB)
// MODE 2: f32 gather straight from emb
template<int MODE>
__global__ __launch_bounds__(256, 3) void nr_main(
    const float* __restrict__ emb, const unsigned short* __restrict__ embh,
    const int* __restrict__ knn,
    const unsigned short* __restrict__ W1T, const unsigned short* __restrict__ W2T,
    const float* __restrict__ b1, const float* __restrict__ b2,
    float* __restrict__ out, int m_start)
{
    __shared__ unsigned short feats[BM * FP];   // 50176 B; reused for h after GEMM1

    const int t      = threadIdx.x;
    const int m_base = m_start + blockIdx.x * BM;   // global row base of this block

    // -------- Phase 1: gather 16 neighbors, mean, build feats (bf16 in LDS)
    {
        const int node_local = t >> 2;          // 0..63
        const int dpart      = t & 3;           // 0..3 -> 32 dims each
        int m = m_base + node_local;            // global node row
        if (MODE == 1) { if (m >= m_start + NB) m = m_start; }   // tail dup
        const int b    = m / NB;
        const int mloc = m - b * NB;

        int idx[KNN];
        const i32x4* kp4 = (const i32x4*)(knn + (long long)m * KNN);
        #pragma unroll
        for (int q = 0; q < 4; ++q) {
            i32x4 v = __builtin_nontemporal_load(kp4 + q);
            idx[4*q+0] = v[0]; idx[4*q+1] = v[1]; idx[4*q+2] = v[2]; idx[4*q+3] = v[3];
        }

        float sm[32];
        #pragma unroll
        for (int e = 0; e < 32; ++e) sm[e] = 0.f;

        unsigned short* frow = feats + node_local * FP + dpart * 32;

        if constexpr (MODE == 2) {
            const float4* xp = (const float4*)(emb + (long long)m * DD + dpart * 32);
            float4 xv[8];
            #pragma unroll
            for (int j = 0; j < 8; ++j) xv[j] = xp[j];
            const long long bbase = (long long)b * NB * DD + dpart * 32;
            #pragma unroll 4
            for (int k = 0; k < KNN; ++k) {
                const float4* np = (const float4*)(emb + bbase + (long long)idx[k] * DD);
                #pragma unroll
                for (int j = 0; j < 8; ++j) {
                    float4 v = np[j];
                    sm[2*j+0] += 0.f;   // (keep indices aligned below)
                    sm[2*j]   -= 0.f;
                    sm[j*4+0] += 0.f;   // no-op, removed by compiler
                    (void)v;
                    sm[j*4+0] += v.x; sm[j*4+1] += v.y; sm[j*4+2] += v.z; sm[j*4+3] += v.w;
                }
            }
            #pragma unroll
            for (int j = 0; j < 8; ++j) {
                u16x8 dummy; (void)dummy;
                float xs[4] = {xv[j].x, xv[j].y, xv[j].z, xv[j].w};
                #pragma unroll
                for (int e = 0; e < 4; ++e) {
                    float mv = sm[j*4+e] * 0.0625f;
                    frow[j*4+e]        = f2bf(xs[e]);
                    frow[128 + j*4+e]  = f2bf(mv);
                    frow[256 + j*4+e]  = f2bf(xs[e] - mv);
                }
            }
        } else {
            const long long xrow = (MODE == 0) ? (long long)m : (long long)mloc;
            u16x8 xv[4];
            const u16x8* xp = (const u16x8*)(embh + xrow * DD + dpart * 32);
            #pragma unroll
            for (int j = 0; j < 4; ++j) xv[j] = xp[j];

            const long long bbase =
                ((MODE == 0) ? (long long)b * NB * DD : 0LL) + dpart * 32;
            #pragma unroll 4
            for (int k = 0; k < KNN; ++k) {
                const u16x8* np = (const u16x8*)(embh + bbase + (long long)idx[k] * DD);
                #pragma unroll
                for (int j = 0; j < 4; ++j) {
                    u16x8 v = np[j];
                    #pragma unroll
                    for (int e = 0; e < 8; ++e) sm[j*8+e] += bf2f(v[e]);
                }
            }
            #pragma unroll
            for (int j = 0; j < 4; ++j) {
                u16x8 pm, pd;
                #pragma unroll
                for (int e = 0; e < 8; ++e) {
                    float mv = sm[j*8+e] * 0.0625f;
                    pm[e] = f2bf(mv);
                    pd[e] = f2bf(bf2f(xv[j][e]) - mv);
                }
                *(u16x8*)(frow + j*8)        = xv[j];  // x
                *(u16x8*)(frow + 128 + j*8)  = pm;     // mean
                *(u16x8*)(frow + 256 + j*8)  = pd;     // x - mean
            }
        }
    }
    __syncthreads();

    // -------- Phase 2: GEMM1  h_pre = feats @ W1   (per-wave 16 rows x 128 cols)
    const int wave = t >> 6;                    // 0..3
    const int lane = t & 63;
    const int lrow = lane & 15;                 // A row / B col / D col
    const int lk   = lane >> 4;                 // 0..3

    f32x4 acc[8];
    #pragma unroll
    for (int f = 0; f < 8; ++f) acc[f] = (f32x4){0.f, 0.f, 0.f, 0.f};

    {
        const unsigned short* abase = feats + (wave * 16 + lrow) * FP + lk * 8;
        #pragma unroll
        for (int ks = 0; ks < 12; ++ks) {
            bf16x8 af = *(const bf16x8*)(abase + ks * 32);
            #pragma unroll
            for (int f = 0; f < 8; ++f) {
                int col = f * 16 + lrow;
                bf16x8 bfr = *(const bf16x8*)(W1T + (long long)col * K3 + ks * 32 + lk * 8);
                acc[f] = __builtin_amdgcn_mfma_f32_16x16x32_bf16(af, bfr, acc[f], 0, 0, 0);
            }
        }
    }
    __syncthreads();                            // all feats reads done -> can overwrite

    // epilogue 1: bias + exact GELU -> h (bf16) into the SAME LDS buffer
    unsigned short* hl = feats;
    #pragma unroll
    for (int f = 0; f < 8; ++f) {
        int col = f * 16 + lrow;
        float bb = b1[col];
        #pragma unroll
        for (int r = 0; r < 4; ++r) {
            int row = wave * 16 + lk * 4 + r;
            float xg = acc[f][r] + bb;
            float hv = 0.5f * xg * (1.0f + erff(xg * 0.70710678118654752f));
            hl[row * HP + col] = f2bf(hv);
        }
    }
    __syncthreads();

    // -------- Phase 3: GEMM2  upd = h @ W2
    f32x4 acc2[8];
    #pragma unroll
    for (int f = 0; f < 8; ++f) acc2[f] = (f32x4){0.f, 0.f, 0.f, 0.f};

    {
        const unsigned short* abase = hl + (wave * 16 + lrow) * HP + lk * 8;
        #pragma unroll
        for (int ks = 0; ks < 4; ++ks) {
            bf16x8 af = *(const bf16x8*)(abase + ks * 32);
            #pragma unroll
            for (int f = 0; f < 8; ++f) {
                int col = f * 16 + lrow;
                bf16x8 bfr = *(const bf16x8*)(W2T + col * DD + ks * 32 + lk * 8);
                acc2[f] = __builtin_amdgcn_mfma_f32_16x16x32_bf16(af, bfr, acc2[f], 0, 0, 0);
            }
        }
    }

    // epilogue 2: residual + bias, fp32 out (streaming: non-temporal)
    #pragma unroll
    for (int f = 0; f < 8; ++f) {
        int col = f * 16 + lrow;
        float bb = b2[col];
        #pragma unroll
        for (int r = 0; r < 4; ++r) {
            int row = wave * 16 + lk * 4 + r;
            int row_g = m_base + row;
            if (MODE == 1 && row_g >= m_start + NB) continue;   // tail guard
            long long o = (long long)row_g * DD + col;
            float res = __builtin_nontemporal_load(emb + o);
            __builtin_nontemporal_store(res + acc2[f][r] + bb, out + o);
        }
    }
}

extern "C" void kernel_launch(void* const* d_in, const int* in_sizes, int n_in,
                              void* d_out, int out_size, void* d_ws, size_t ws_size,
                              hipStream_t stream) {
    const float* emb = (const float*)d_in[0];   // [B,N,D] f32
    const int*   knn = (const int*)  d_in[1];   // [B,N,K] i32
    const float* W1  = (const float*)d_in[2];   // [384,128]
    const float* b1  = (const float*)d_in[3];   // [128]
    const float* W2  = (const float*)d_in[4];   // [128,128]
    const float* b2  = (const float*)d_in[5];   // [128]
    float* out = (float*)d_out;

    unsigned short* W1T  = (unsigned short*)d_ws;           // 49152 u16
    unsigned short* W2T  = W1T + 128 * K3;                  // 16384 u16
    unsigned short* embh = W2T + 128 * DD;                  // table region

    const size_t NEED_T1 = (size_t)(65536 + 10240000) * 2;  // full bf16 table
    const size_t NEED_T2 = (size_t)(65536 + 2560000) * 2;   // one-batch bf16 table

    nr_prep_w<<<256, 256, 0, stream>>>(W1, W2, W1T, W2T);

    if (ws_size >= NEED_T1) {
        // T1: full table, single main launch
        nr_prep_emb<<<5000, 256, 0, stream>>>(emb, embh);   // 5000*2048 = 10.24M
        nr_main<0><<<M_TOTAL / BM, 256, 0, stream>>>(emb, embh, knn, W1T, W2T,
                                                     b1, b2, out, 0);
    } else if (ws_size >= NEED_T2) {
        // T2: per-batch table, 4 sequential (prep, main) pairs
        const int blocks_b = (NB + BM - 1) / BM;            // 313 (tail-guarded)
        for (int b = 0; b < BATCH; ++b) {
            nr_prep_emb<<<1250, 256, 0, stream>>>(emb + (long long)b * NB * DD, embh);
            nr_main<1><<<blocks_b, 256, 0, stream>>>(emb, embh, knn, W1T, W2T,
                                                     b1, b2, out, b * NB);
        }
    } else {
        // T3: f32 gather fallback (needs only the 128 KiB weight region)
        nr_main<2><<<M_TOTAL / BM, 256, 0, stream>>>(emb, nullptr, knn, W1T, W2T,
                                                     b1, b2, out, 0);
    }
}